// Round 1
// baseline (92.949 us; speedup 1.0000x reference)
//
#include <hip/hip_runtime.h>
#include <math.h>

// Problem constants (from reference)
#define BB 4096
#define PP 128
#define GG 128

// SCALE = SPACE_SIZE / (VOXELS_PER_AXIS - 1), BIAS = SPACE_CENTER - SPACE_SIZE/2
#define SCALE_X (8000.0f / 79.0f)
#define SCALE_Y (8000.0f / 79.0f)
#define SCALE_Z (2000.0f / 19.0f)
#define BIAS_X (-4000.0f)
#define BIAS_Y (-4000.0f)
#define BIAS_Z (0.0f)

#define DIST_THRESH_SQ (500.0f * 500.0f)
#define BBOX_THRESH 0.1f

__global__ __launch_bounds__(PP) void proposal_layer_kernel(
    const int* __restrict__ topk_index,        // [B, P, 3]
    const float* __restrict__ topk_confs,      // [B, P]
    const float* __restrict__ match_bbox_preds,// [B, P, 2]
    const float* __restrict__ roots_3d,        // [B, G, 3]
    const float* __restrict__ gt_bbox,         // [B, G, 2]
    const int* __restrict__ num_person,        // [B]
    float* __restrict__ out)                   // [B, P, 7]
{
    const int b = blockIdx.x;
    const int p = threadIdx.x;

    __shared__ float s_roots[GG][3];
    __shared__ float s_bbox[GG][2];

    // Stage this batch's GT roots and bboxes into LDS.
    for (int i = threadIdx.x; i < GG * 3; i += PP) {
        s_roots[i / 3][i % 3] = roots_3d[(size_t)b * GG * 3 + i];
    }
    for (int i = threadIdx.x; i < GG * 2; i += PP) {
        s_bbox[i / 2][i % 2] = gt_bbox[(size_t)b * GG * 2 + i];
    }
    const int np = num_person[b];
    __syncthreads();

    // voxel index -> world coords
    const size_t bp = (size_t)b * PP + p;
    const int ix = topk_index[bp * 3 + 0];
    const int iy = topk_index[bp * 3 + 1];
    const int iz = topk_index[bp * 3 + 2];
    const float cx = (float)ix * SCALE_X + BIAS_X;
    const float cy = (float)iy * SCALE_Y + BIAS_Y;
    const float cz = (float)iz * SCALE_Z + BIAS_Z;

    // nearest valid GT (first-minimum tie-break, matching jnp.argmin)
    float best = INFINITY;
    int besti = 0;
    for (int g = 0; g < np; ++g) {
        const float dx = cx - s_roots[g][0];
        const float dy = cy - s_roots[g][1];
        const float dz = cz - s_roots[g][2];
        const float d2 = dx * dx + dy * dy + dz * dz;
        if (d2 < best) { best = d2; besti = g; }
    }

    const float p2g = (best > DIST_THRESH_SQ) ? -1.0f : (float)besti;
    // clip(p2g, 0, G-1): -1 -> 0, matched index already in range
    const int safe = (p2g < 0.0f) ? 0 : besti;
    const float mb0 = s_bbox[safe][0];
    const float mb1 = s_bbox[safe][1];

    const float pb0 = match_bbox_preds[bp * 2 + 0];
    const float pb1 = match_bbox_preds[bp * 2 + 1];
    const bool overwrite = (p2g >= 0.0f) &&
                           ((pb0 < mb0 - BBOX_THRESH) || (pb1 < mb1 - BBOX_THRESH));
    const float o0 = overwrite ? mb0 : pb0;
    const float o1 = overwrite ? mb1 : pb1;

    float* op = out + bp * 7;
    op[0] = cx;
    op[1] = cy;
    op[2] = cz;
    op[3] = p2g;
    op[4] = topk_confs[bp];
    op[5] = o0;
    op[6] = o1;
}

extern "C" void kernel_launch(void* const* d_in, const int* in_sizes, int n_in,
                              void* d_out, int out_size, void* d_ws, size_t ws_size,
                              hipStream_t stream) {
    const int* topk_index = (const int*)d_in[0];
    const float* topk_confs = (const float*)d_in[1];
    const float* match_bbox_preds = (const float*)d_in[2];
    const float* roots_3d = (const float*)d_in[3];
    const float* gt_bbox = (const float*)d_in[4];
    const int* num_person = (const int*)d_in[5];
    float* out = (float*)d_out;

    proposal_layer_kernel<<<BB, PP, 0, stream>>>(
        topk_index, topk_confs, match_bbox_preds, roots_3d, gt_bbox, num_person, out);
}